// Round 8
// baseline (470.088 us; speedup 1.0000x reference)
//
#include <hip/hip_runtime.h>

// Problem constants (B,S,H,D fixed by the reference)
#define BB   2
#define SS   2048
#define HH   16
#define DD   64
#define CC   128               // chunk length
#define NCH  (SS/CC)           // 16 chunks per (b,h)
#define RECF (DD*DD + DD)      // 4160 elems per record: State^T rows 0..63 + ksum row 64
#define BHN  (BB*HH)           // 32
#define NCHK (BHN*NCH)         // 512 blocks = exactly 2/CU x 256 CUs (co-resident)

typedef __attribute__((ext_vector_type(8))) short short8;
typedef __attribute__((ext_vector_type(4))) float f32x4;

// XOR swizzle of the s-index (units of 8 shorts) by LDS row.
#define SW(r) ((((r) >> 3) & 7) << 3)

__device__ __forceinline__ float elu1(float x) {
    return x > 0.0f ? x + 1.0f : __expf(x);
}
__device__ __forceinline__ short f2bf(float f) {
    union { float f; unsigned u; } x; x.f = f;
    unsigned r = x.u + 0x7FFFu + ((x.u >> 16) & 1u);   // RNE
    return (short)(r >> 16);
}
__device__ __forceinline__ float bf2f(short s) {
    union { unsigned u; float f; } x; x.u = ((unsigned)(unsigned short)s) << 16;
    return x.f;
}

// LDS layout (units: shorts), 31952 shorts = 63904 B (coop-validated in R7).
//   R0 [0,9216):        phaseA KT[64][136] / phaseB Sbh[128][72]
//   R1 [9216,13896):    StT[65][72]   (row 64 = ksum prefix)
//   R2 [13896,22736):   VT[65][136]   (rows 0-63 = V^T swizzled, row 64 = ones)
//   R3 [22736,31952):   Kb[128][72]   (K row-major bf16)
// tc=4 / rt=4 B-tile row reads clamp to row 64 (ones/ksum broadcast) -> the
// denominator lands in every lane of acc[4]; no undeclared-row reads.
#define OFF_STT 9216
#define OFF_VT  13896
#define OFF_KB  22736
#define NSMEM   31952

__global__ __launch_bounds__(512, 4) void k_fused(const float* __restrict__ qk,
                                                  const float* __restrict__ v,
                                                  short* __restrict__ rec_g,
                                                  int* __restrict__ flags,
                                                  float* __restrict__ out) {
    const int blk = blockIdx.x;
    const int c   = blk % NCH;
    const int bh  = blk / NCH;
    const int b = bh / HH, h = bh % HH;
    const int tid = threadIdx.x;
    const int w   = tid >> 6;
    const int l   = tid & 63;
    const int l15 = l & 15;
    const int g   = l >> 4;

    __shared__ __align__(16) short smem[NSMEM];
    short (*KT) [136] = (short(*)[136])(smem);
    short (*Sbh)[72]  = (short(*)[72]) (smem);
    short (*StT)[72]  = (short(*)[72]) (smem + OFF_STT);
    short (*VT) [136] = (short(*)[136])(smem + OFF_VT);
    short (*Kb) [72]  = (short(*)[72]) (smem + OFF_KB);

    // ================= Phase A: stage K/V, compute + publish chunk State^T ==
#pragma unroll
    for (int it = 0; it < 4; ++it) {
        const int f    = tid + it*512;      // float4 index 0..2047
        const int row  = f >> 4;            // s in chunk, 0..127
        const int col4 = (f & 15) * 4;      // d
        const int s = c*CC + row;
        float4 kq = *(const float4*)(qk + ((((size_t)b*SS + s)*2 + 1)*HH + h)*DD + col4);
        short4 kb;
        kb.x = f2bf(elu1(kq.x)); kb.y = f2bf(elu1(kq.y));
        kb.z = f2bf(elu1(kq.z)); kb.w = f2bf(elu1(kq.w));
        *(short4*)(&Kb[row][col4]) = kb;
        KT[col4+0][row ^ SW(col4+0)] = kb.x;
        KT[col4+1][row ^ SW(col4+1)] = kb.y;
        KT[col4+2][row ^ SW(col4+2)] = kb.z;
        KT[col4+3][row ^ SW(col4+3)] = kb.w;
        float4 vv = *(const float4*)(v + (((size_t)b*SS + s)*HH + h)*DD + col4);
        VT[col4+0][row ^ SW(col4+0)] = f2bf(vv.x);
        VT[col4+1][row ^ SW(col4+1)] = f2bf(vv.y);
        VT[col4+2][row ^ SW(col4+2)] = f2bf(vv.z);
        VT[col4+3][row ^ SW(col4+3)] = f2bf(vv.w);
    }
    if (tid < 128) VT[64][tid] = (short)0x3F80;   // ones row (SW(64)==0)

    // Early Q loads (raw fp32) — drain under phase-A MFMAs.
    const int qrow = 16*w + l15;
    const float* qp = qk + ((((size_t)b*SS + (c*CC + qrow))*2 + 0)*HH + h)*DD;
    float4 q0 = *(const float4*)(qp + 8*g);
    float4 q1 = *(const float4*)(qp + 8*g + 4);
    float4 q2 = *(const float4*)(qp + 32 + 8*g);
    float4 q3 = *(const float4*)(qp + 32 + 8*g + 4);

    __syncthreads();

    // State^T[t][d] (+ksum row 64) = [V^T; ones] . K. d-tile = w&3,
    // row-tile half = w>>2 (half 0: rt 0..2, half 1: rt 3..4).
    {
        const int dtile = w & 3;
        const int half  = w >> 2;
        const int nrt   = half ? 2 : 3;
        const int rt0   = half ? 3 : 0;
        f32x4 acc1[3];
#pragma unroll
        for (int i = 0; i < 3; ++i) acc1[i] = (f32x4){0.f,0.f,0.f,0.f};
        const int krow = 16*dtile + l15;
#pragma unroll
        for (int ks = 0; ks < 4; ++ks) {
            const int cb = 32*ks + 8*g;
            short8 bk = *(const short8*)(&KT[krow][cb ^ SW(krow)]);
#pragma unroll
            for (int i = 0; i < 3; ++i) {
                if (i < nrt) {
                    int arow = 16*(rt0 + i) + l15;
                    if (arow > 64) arow = 64;          // clamp into ones row
                    short8 a = *(const short8*)(&VT[arow][cb ^ SW(arow)]);
                    acc1[i] = __builtin_amdgcn_mfma_f32_16x16x32_bf16(a, bk, acc1[i], 0, 0, 0);
                }
            }
        }
        short* rec = rec_g + (size_t)blk * RECF;
#pragma unroll
        for (int i = 0; i < 3; ++i) {
            if (i < nrt) {
                const int rt = rt0 + i;
                if (rt < 4) {
#pragma unroll
                    for (int e = 0; e < 4; ++e)
                        rec[(16*rt + 4*g + e)*DD + 16*dtile + l15] = f2bf(acc1[i][e]);
                } else if (g == 0) {
                    rec[4096 + 16*dtile + l15] = f2bf(acc1[i][0]);   // ksum row
                }
            }
        }
    }

    __syncthreads();            // all rec writes + KT reads complete
    __threadfence();            // device-scope: make rec visible cross-XCD
    if (tid == 0)
        __hip_atomic_store(&flags[blk], 1, __ATOMIC_RELEASE, __HIP_MEMORY_SCOPE_AGENT);

    // ================= Phase B: O = [S | Q] . [V;ones ; State^T;ksum] =======
    short8 aq[2];
    {
        short8 a;
        a[0] = f2bf(elu1(q0.x)); a[1] = f2bf(elu1(q0.y));
        a[2] = f2bf(elu1(q0.z)); a[3] = f2bf(elu1(q0.w));
        a[4] = f2bf(elu1(q1.x)); a[5] = f2bf(elu1(q1.y));
        a[6] = f2bf(elu1(q1.z)); a[7] = f2bf(elu1(q1.w));
        aq[0] = a;
        a[0] = f2bf(elu1(q2.x)); a[1] = f2bf(elu1(q2.y));
        a[2] = f2bf(elu1(q2.z)); a[3] = f2bf(elu1(q2.w));
        a[4] = f2bf(elu1(q3.x)); a[5] = f2bf(elu1(q3.y));
        a[6] = f2bf(elu1(q3.z)); a[7] = f2bf(elu1(q3.w));
        aq[1] = a;
    }

    const int rowb = 16*w + 4*g;

    // ---- S half A: cols s in [0,64) -> Sbh (overwrites dead KT) ----
#pragma unroll
    for (int tc = 0; tc < 4; ++tc) {
        f32x4 sacc = {0.f,0.f,0.f,0.f};
#pragma unroll
        for (int ks = 0; ks < 2; ++ks) {
            short8 bk = *(const short8*)(&Kb[16*tc + l15][32*ks + 8*g]);
            sacc = __builtin_amdgcn_mfma_f32_16x16x32_bf16(aq[ks], bk, sacc, 0, 0, 0);
        }
        const int colg = 16*tc + l15;
#pragma unroll
        for (int e = 0; e < 4; ++e) {
            const float sv = (colg <= rowb + e) ? sacc[e] : 0.0f;
            Sbh[rowb + e][colg] = f2bf(sv);
        }
    }
    __syncthreads();

    // ---- O += S_A.V (kj 0,1); tile 4 = denominator column ----
    f32x4 acc[5];
#pragma unroll
    for (int t = 0; t < 5; ++t) acc[t] = (f32x4){0.f,0.f,0.f,0.f};
#pragma unroll
    for (int kj = 0; kj < 2; ++kj) {
        short8 as = *(const short8*)(&Sbh[16*w + l15][32*kj + 8*g]);
#pragma unroll
        for (int tc = 0; tc < 5; ++tc) {
            int vrow = 16*tc + l15;
            if (vrow > 64) vrow = 64;                  // clamp into ones row
            short8 bv = *(const short8*)(&VT[vrow][(32*kj + 8*g) ^ SW(vrow)]);
            acc[tc] = __builtin_amdgcn_mfma_f32_16x16x32_bf16(as, bv, acc[tc], 0, 0, 0);
        }
    }

    // ---- decoupled lookback: prefix = sum of predecessor chunk states ----
    float pf[8] = {0.f,0.f,0.f,0.f,0.f,0.f,0.f,0.f};
    float pk[8] = {0.f,0.f,0.f,0.f,0.f,0.f,0.f,0.f};
    if (c > 0) {
#pragma unroll 1
        for (int p = 0; p < c; ++p) {
            while (__hip_atomic_load(&flags[bh*NCH + p], __ATOMIC_ACQUIRE,
                                     __HIP_MEMORY_SCOPE_AGENT) == 0)
                __builtin_amdgcn_s_sleep(1);
        }
#pragma unroll 1
        for (int p = 0; p < c; ++p) {
            const short* rr = rec_g + (size_t)(bh*NCH + p)*RECF;
            short8 rv = *(const short8*)(rr + tid*8);
#pragma unroll
            for (int e = 0; e < 8; ++e) pf[e] += bf2f(rv[e]);
            if (tid < 8) {
                short8 kv = *(const short8*)(rr + 4096 + tid*8);
#pragma unroll
                for (int e = 0; e < 8; ++e) pk[e] += bf2f(kv[e]);
            }
        }
    }
    {
        short8 sv;
#pragma unroll
        for (int e = 0; e < 8; ++e) sv[e] = f2bf(pf[e]);
        *(short8*)(&StT[tid >> 3][(tid & 7) * 8]) = sv;
        if (tid < 8) {
            short8 s2;
#pragma unroll
            for (int e = 0; e < 8; ++e) s2[e] = f2bf(pk[e]);
            *(short8*)(&StT[64][tid * 8]) = s2;
        }
    }
    __syncthreads();   // S_A consumed; StT visible

    // ---- S half B: cols s in [64,128) -> Sbh (local col = colg-64) ----
#pragma unroll
    for (int tc = 4; tc < 8; ++tc) {
        f32x4 sacc = {0.f,0.f,0.f,0.f};
#pragma unroll
        for (int ks = 0; ks < 2; ++ks) {
            short8 bk = *(const short8*)(&Kb[16*tc + l15][32*ks + 8*g]);
            sacc = __builtin_amdgcn_mfma_f32_16x16x32_bf16(aq[ks], bk, sacc, 0, 0, 0);
        }
        const int colg = 16*tc + l15;
#pragma unroll
        for (int e = 0; e < 4; ++e) {
            const float sv = (colg <= rowb + e) ? sacc[e] : 0.0f;
            Sbh[rowb + e][colg - 64] = f2bf(sv);
        }
    }
    __syncthreads();

    // ---- O += S_B.V (kj 2,3) + Q.State^T (kd 0,1) ----
#pragma unroll
    for (int kj = 2; kj < 4; ++kj) {
        short8 as = *(const short8*)(&Sbh[16*w + l15][32*(kj-2) + 8*g]);
#pragma unroll
        for (int tc = 0; tc < 5; ++tc) {
            int vrow = 16*tc + l15;
            if (vrow > 64) vrow = 64;
            short8 bv = *(const short8*)(&VT[vrow][(32*kj + 8*g) ^ SW(vrow)]);
            acc[tc] = __builtin_amdgcn_mfma_f32_16x16x32_bf16(as, bv, acc[tc], 0, 0, 0);
        }
    }
#pragma unroll
    for (int kd = 0; kd < 2; ++kd) {
#pragma unroll
        for (int tc = 0; tc < 5; ++tc) {
            int srow = 16*tc + l15;
            if (srow > 64) srow = 64;                  // clamp into ksum row
            short8 bs = *(const short8*)(&StT[srow][32*kd + 8*g]);
            acc[tc] = __builtin_amdgcn_mfma_f32_16x16x32_bf16(aq[kd], bs, acc[tc], 0, 0, 0);
        }
    }

    // ---- epilogue: acc[4][e] IS the denominator in every lane ----
    float rn[4];
#pragma unroll
    for (int e = 0; e < 4; ++e) rn[e] = 1.0f / acc[4][e];
    const int rowg = c*CC + rowb;
#pragma unroll
    for (int e = 0; e < 4; ++e) {
        float* orow = out + (((size_t)b*SS + rowg + e)*HH + h)*DD + l15;
#pragma unroll
        for (int tc = 0; tc < 4; ++tc) orow[16*tc] = acc[tc][e] * rn[e];
    }
}

// ---------------------------------------------------------------------------
extern "C" void kernel_launch(void* const* d_in, const int* in_sizes, int n_in,
                              void* d_out, int out_size, void* d_ws, size_t ws_size,
                              hipStream_t stream) {
    const float* qk = (const float*)d_in[0];
    const float* v  = (const float*)d_in[1];
    float* out = (float*)d_out;

    short* rec_g = (short*)d_ws;                          // 512*4160 bf16 = 4.26 MB
    int*   flags = (int*)((char*)d_ws + (8u << 20));      // past rec, 2 KB

    hipMemsetAsync(flags, 0, NCHK * sizeof(int), stream); // captured memset node

    void* args[] = { (void*)&qk, (void*)&v, (void*)&rec_g, (void*)&flags, (void*)&out };
    hipError_t le = hipLaunchCooperativeKernel((const void*)k_fused, dim3(NCHK),
                                               dim3(512), args, 0, stream);
    if (le != hipSuccess) {
        // exact-capacity grid (512 = 2/CU x 256 CU) keeps the spin safe
        k_fused<<<dim3(NCHK), dim3(512), 0, stream>>>(qk, v, rec_g, flags, out);
    }
}

// Round 9
// 31.338 us; speedup vs baseline: 15.0007x; 15.0007x over previous
//
#include <hip/hip_runtime.h>

// Problem constants (B,S,H,D fixed by the reference)
#define BB   2
#define SS   2048
#define HH   16
#define DD   64
#define CC   128               // chunk length
#define NCH  (SS/CC)           // 16 chunks per (b,h)
#define RECF (DD*DD + DD)      // 4160 elems per record: State^T rows 0..63 + ksum row 64
#define BHN  (BB*HH)           // 32
#define NCHK (BHN*NCH)         // 512 chunk-blocks

typedef __attribute__((ext_vector_type(8))) short short8;
typedef __attribute__((ext_vector_type(4))) float f32x4;

// XOR swizzle of the s-index (units of 8 shorts) by LDS row.
#define SW(r) ((((r) >> 3) & 7) << 3)

__device__ __forceinline__ float elu1(float x) {
    return x > 0.0f ? x + 1.0f : __expf(x);
}
__device__ __forceinline__ short f2bf(float f) {
    union { float f; unsigned u; } x; x.f = f;
    unsigned r = x.u + 0x7FFFu + ((x.u >> 16) & 1u);   // RNE
    return (short)(r >> 16);
}
__device__ __forceinline__ float bf2f(short s) {
    union { unsigned u; float f; } x; x.u = ((unsigned)(unsigned short)s) << 16;
    return x.f;
}

// ---------------------------------------------------------------------------
// Kernel 1: per-chunk State^T (+ksum row) = [V^T; ones] . K  -> rec_g (bf16).
// 512 threads = 8 waves; d-tile = w&3, row-tile half = w>>2.
// LDS 35.1 KB -> 4 blocks/CU.
// ---------------------------------------------------------------------------
__global__ __launch_bounds__(512) void k_state(const float* __restrict__ qk,
                                               const float* __restrict__ v,
                                               short* __restrict__ rec_g) {
    const int blk = blockIdx.x;
    const int c   = blk % NCH;
    const int bh  = blk / NCH;
    const int b = bh / HH, h = bh % HH;
    const int tid = threadIdx.x;
    const int w   = tid >> 6;
    const int l   = tid & 63;
    const int l15 = l & 15;
    const int g   = l >> 4;

    __shared__ short KT[64][136];   // K^T, swizzled cols
    __shared__ short VT[65][136];   // V^T + ones row 64

#pragma unroll
    for (int it = 0; it < 4; ++it) {
        const int f    = tid + it*512;      // float4 index 0..2047
        const int row  = f >> 4;            // s in chunk, 0..127
        const int col4 = (f & 15) * 4;      // d
        const int s = c*CC + row;
        float4 kq = *(const float4*)(qk + ((((size_t)b*SS + s)*2 + 1)*HH + h)*DD + col4);
        KT[col4+0][row ^ SW(col4+0)] = f2bf(elu1(kq.x));
        KT[col4+1][row ^ SW(col4+1)] = f2bf(elu1(kq.y));
        KT[col4+2][row ^ SW(col4+2)] = f2bf(elu1(kq.z));
        KT[col4+3][row ^ SW(col4+3)] = f2bf(elu1(kq.w));
        float4 vv = *(const float4*)(v + (((size_t)b*SS + s)*HH + h)*DD + col4);
        VT[col4+0][row ^ SW(col4+0)] = f2bf(vv.x);
        VT[col4+1][row ^ SW(col4+1)] = f2bf(vv.y);
        VT[col4+2][row ^ SW(col4+2)] = f2bf(vv.z);
        VT[col4+3][row ^ SW(col4+3)] = f2bf(vv.w);
    }
    if (tid < 128) VT[64][tid] = (short)0x3F80;   // ones row (SW(64)==0)
    __syncthreads();

    const int dtile = w & 3;
    const int half  = w >> 2;
    const int nrt   = half ? 2 : 3;
    const int rt0   = half ? 3 : 0;
    f32x4 acc1[3];
#pragma unroll
    for (int i = 0; i < 3; ++i) acc1[i] = (f32x4){0.f,0.f,0.f,0.f};
    const int krow = 16*dtile + l15;
#pragma unroll
    for (int ks = 0; ks < 4; ++ks) {
        const int cb = 32*ks + 8*g;
        short8 bk = *(const short8*)(&KT[krow][cb ^ SW(krow)]);
#pragma unroll
        for (int i = 0; i < 3; ++i) {
            if (i < nrt) {
                int arow = 16*(rt0 + i) + l15;
                if (arow > 64) arow = 64;          // clamp into ones row
                short8 a = *(const short8*)(&VT[arow][cb ^ SW(arow)]);
                acc1[i] = __builtin_amdgcn_mfma_f32_16x16x32_bf16(a, bk, acc1[i], 0, 0, 0);
            }
        }
    }
    short* rec = rec_g + (size_t)blk * RECF;
#pragma unroll
    for (int i = 0; i < 3; ++i) {
        if (i < nrt) {
            const int rt = rt0 + i;
            if (rt < 4) {
#pragma unroll
                for (int e = 0; e < 4; ++e)
                    rec[(16*rt + 4*g + e)*DD + 16*dtile + l15] = f2bf(acc1[i][e]);
            } else if (g == 0) {
                rec[4096 + 16*dtile + l15] = f2bf(acc1[i][0]);   // ksum row
            }
        }
    }
}

// ---------------------------------------------------------------------------
// Kernel 2: O = [S | Q] . [V;ones ; State_prefix^T;ksum], S = mask(Q K^T).
// K/V staged directly from qk/v (L3-resident after k1). The chunk-prefix is
// computed in-kernel: sum of predecessor records (<=15 predicated unrolled
// loads, ascending-order fp32 adds == old scan order, bit-identical).
// LDS 63.9 KB -> 2 blocks/CU. Clamp-row trick: denominator in every lane.
// ---------------------------------------------------------------------------
__global__ __launch_bounds__(512) void k_out(const float* __restrict__ qk,
                                             const float* __restrict__ v,
                                             const short* __restrict__ rec_g,
                                             float* __restrict__ out) {
    const int blk = blockIdx.x;
    const int c   = blk % NCH;
    const int bh  = blk / NCH;
    const int b = bh / HH, h = bh % HH;
    const int tid = threadIdx.x;
    const int w   = tid >> 6;
    const int l   = tid & 63;
    const int l15 = l & 15;
    const int g   = l >> 4;

    __shared__ short Sbh[128][72];  // score half (two passes)        18432 B
    __shared__ short StT[65][72];   // prefix State^T + ksum row 64    9360 B
    __shared__ short VT[65][136];   // V^T + ones row 64              17680 B
    __shared__ short Kb[128][72];   // K row-major bf16               18432 B

    // ---- stage Kb (coalesced) + VT (transposed writes) from qk/v ----
#pragma unroll
    for (int it = 0; it < 4; ++it) {
        const int f    = tid + it*512;      // float4 index 0..2047
        const int row  = f >> 4;
        const int col4 = (f & 15) * 4;
        const int s = c*CC + row;
        float4 kq = *(const float4*)(qk + ((((size_t)b*SS + s)*2 + 1)*HH + h)*DD + col4);
        short4 kb;
        kb.x = f2bf(elu1(kq.x)); kb.y = f2bf(elu1(kq.y));
        kb.z = f2bf(elu1(kq.z)); kb.w = f2bf(elu1(kq.w));
        *(short4*)(&Kb[row][col4]) = kb;
        float4 vv = *(const float4*)(v + (((size_t)b*SS + s)*HH + h)*DD + col4);
        VT[col4+0][row ^ SW(col4+0)] = f2bf(vv.x);
        VT[col4+1][row ^ SW(col4+1)] = f2bf(vv.y);
        VT[col4+2][row ^ SW(col4+2)] = f2bf(vv.z);
        VT[col4+3][row ^ SW(col4+3)] = f2bf(vv.w);
    }
    if (tid < 128) VT[64][tid] = (short)0x3F80;   // ones row

    // ---- Q fragments (elu1 -> bf16) ----
    const int qrow = 16*w + l15;
    const float* qp = qk + ((((size_t)b*SS + (c*CC + qrow))*2 + 0)*HH + h)*DD;
    short8 aq[2];
#pragma unroll
    for (int ks = 0; ks < 2; ++ks) {
        const int k0 = 32*ks + 8*g;
        float4 t0 = *(const float4*)(qp + k0);
        float4 t1 = *(const float4*)(qp + k0 + 4);
        short8 a;
        a[0] = f2bf(elu1(t0.x)); a[1] = f2bf(elu1(t0.y));
        a[2] = f2bf(elu1(t0.z)); a[3] = f2bf(elu1(t0.w));
        a[4] = f2bf(elu1(t1.x)); a[5] = f2bf(elu1(t1.y));
        a[6] = f2bf(elu1(t1.z)); a[7] = f2bf(elu1(t1.w));
        aq[ks] = a;
    }

    // ---- in-kernel lookback: prefix = sum of predecessor chunk records ----
    // All loads issued unconditionally (clamped address), unrolled -> regs;
    // adds predicated and ascending in p (matches old scan order exactly).
    {
        const short* base = rec_g + (size_t)(bh*NCH) * RECF;
        float pf[8] = {0.f,0.f,0.f,0.f,0.f,0.f,0.f,0.f};
        short8 rv[15];
#pragma unroll
        for (int p = 0; p < 15; ++p) {
            const int pp = (p < c) ? p : 0;        // safe, always-valid address
            rv[p] = *(const short8*)(base + (size_t)pp*RECF + tid*8);
        }
#pragma unroll
        for (int p = 0; p < 15; ++p) {
            if (p < c) {
#pragma unroll
                for (int e = 0; e < 8; ++e) pf[e] += bf2f(rv[p][e]);
            }
        }
        short8 sv;
#pragma unroll
        for (int e = 0; e < 8; ++e) sv[e] = f2bf(pf[e]);
        *(short8*)(&StT[tid >> 3][(tid & 7) * 8]) = sv;

        if (tid < 64) {                             // ksum row: one elem/lane
            float ps = 0.f;
#pragma unroll
            for (int p = 0; p < 15; ++p) {
                const int pp = (p < c) ? p : 0;
                const float kv = bf2f(base[(size_t)pp*RECF + 4096 + tid]);
                if (p < c) ps += kv;
            }
            StT[64][tid] = f2bf(ps);
        }
    }
    __syncthreads();

    const int rowb = 16*w + 4*g;

    // ---- S half A: cols s in [0,64) -> Sbh ----
#pragma unroll
    for (int tc = 0; tc < 4; ++tc) {
        f32x4 sacc = {0.f,0.f,0.f,0.f};
#pragma unroll
        for (int ks = 0; ks < 2; ++ks) {
            short8 bk = *(const short8*)(&Kb[16*tc + l15][32*ks + 8*g]);
            sacc = __builtin_amdgcn_mfma_f32_16x16x32_bf16(aq[ks], bk, sacc, 0, 0, 0);
        }
        const int colg = 16*tc + l15;
#pragma unroll
        for (int e = 0; e < 4; ++e) {
            const float sv = (colg <= rowb + e) ? sacc[e] : 0.0f;
            Sbh[rowb + e][colg] = f2bf(sv);
        }
    }
    __syncthreads();

    // ---- O += S_A.V (kj 0,1) + Q.State^T (kd 0,1); tile 4 = denominator ----
    f32x4 acc[5];
#pragma unroll
    for (int t = 0; t < 5; ++t) acc[t] = (f32x4){0.f,0.f,0.f,0.f};
#pragma unroll
    for (int kj = 0; kj < 2; ++kj) {
        short8 as = *(const short8*)(&Sbh[16*w + l15][32*kj + 8*g]);
#pragma unroll
        for (int tc = 0; tc < 5; ++tc) {
            int vrow = 16*tc + l15;
            if (vrow > 64) vrow = 64;              // clamp into ones row
            short8 bv = *(const short8*)(&VT[vrow][(32*kj + 8*g) ^ SW(vrow)]);
            acc[tc] = __builtin_amdgcn_mfma_f32_16x16x32_bf16(as, bv, acc[tc], 0, 0, 0);
        }
    }
#pragma unroll
    for (int kd = 0; kd < 2; ++kd) {
#pragma unroll
        for (int tc = 0; tc < 5; ++tc) {
            int srow = 16*tc + l15;
            if (srow > 64) srow = 64;              // clamp into ksum row
            short8 bs = *(const short8*)(&StT[srow][32*kd + 8*g]);
            acc[tc] = __builtin_amdgcn_mfma_f32_16x16x32_bf16(aq[kd], bs, acc[tc], 0, 0, 0);
        }
    }
    __syncthreads();

    // ---- S half B: cols s in [64,128) -> Sbh (local col = colg-64) ----
#pragma unroll
    for (int tc = 4; tc < 8; ++tc) {
        f32x4 sacc = {0.f,0.f,0.f,0.f};
#pragma unroll
        for (int ks = 0; ks < 2; ++ks) {
            short8 bk = *(const short8*)(&Kb[16*tc + l15][32*ks + 8*g]);
            sacc = __builtin_amdgcn_mfma_f32_16x16x32_bf16(aq[ks], bk, sacc, 0, 0, 0);
        }
        const int colg = 16*tc + l15;
#pragma unroll
        for (int e = 0; e < 4; ++e) {
            const float sv = (colg <= rowb + e) ? sacc[e] : 0.0f;
            Sbh[rowb + e][colg - 64] = f2bf(sv);
        }
    }
    __syncthreads();

    // ---- O += S_B.V (kj 2,3; global s = 64 + local) ----
#pragma unroll
    for (int kj = 2; kj < 4; ++kj) {
        short8 as = *(const short8*)(&Sbh[16*w + l15][32*(kj-2) + 8*g]);
#pragma unroll
        for (int tc = 0; tc < 5; ++tc) {
            int vrow = 16*tc + l15;
            if (vrow > 64) vrow = 64;
            short8 bv = *(const short8*)(&VT[vrow][(32*kj + 8*g) ^ SW(vrow)]);
            acc[tc] = __builtin_amdgcn_mfma_f32_16x16x32_bf16(as, bv, acc[tc], 0, 0, 0);
        }
    }

    // ---- epilogue: acc[4][e] IS the denominator in every lane ----
    float rn[4];
#pragma unroll
    for (int e = 0; e < 4; ++e) rn[e] = 1.0f / acc[4][e];
    const int rowg = c*CC + rowb;
#pragma unroll
    for (int e = 0; e < 4; ++e) {
        float* orow = out + (((size_t)b*SS + rowg + e)*HH + h)*DD + l15;
#pragma unroll
        for (int tc = 0; tc < 4; ++tc) orow[16*tc] = acc[tc][e] * rn[e];
    }
}

// ---------------------------------------------------------------------------
extern "C" void kernel_launch(void* const* d_in, const int* in_sizes, int n_in,
                              void* d_out, int out_size, void* d_ws, size_t ws_size,
                              hipStream_t stream) {
    const float* qk = (const float*)d_in[0];
    const float* v  = (const float*)d_in[1];
    float* out = (float*)d_out;

    short* rec_g = (short*)d_ws;        // 512*4160 bf16 = 4.26 MB

    k_state<<<dim3(NCHK), dim3(512), 0, stream>>>(qk, v, rec_g);
    k_out  <<<dim3(NCHK), dim3(512), 0, stream>>>(qk, v, rec_g, out);
}